// Round 6
// baseline (279.639 us; speedup 1.0000x reference)
//
#include <hip/hip_runtime.h>
#include <math.h>

// Problem: B=32, S=2048, H=1024
//   d_out (float): [0] loss | [1..131073) logits (32,2048,2) | [131073..196609) header_mask
//
// R15: GEMM-loop structure attacks exhausted (R10/R12/R13 schedule, R11 staging,
// R14 occupancy: all null or regress; loop sits at the documented m97-structure
// ceiling ~830-910 TF). Instead, delete sr_conv_enc (~60us, 402MB BW) by removing
// A from LDS entirely: 8 waves x (32 rows x 256 cols) output -> each wave's A
// fragments are unique, so A is loaded per-lane DIRECTLY from enc (f32) in exact
// MFMA fragment layout (row=..+l15, k=kt*64+kk*32+lq*8 — algebra matches R9's
// swizzled STAGE/read pair), converted in-register with the same (__bf16) cast.
// A-prefetch one tile ahead; the per-tile __syncthreads vmcnt-drain certifies
// the (per-wave-private) registers for free. B keeps the proven DMA+swizzle
// path (reads double to 32 b128/wave/tile but LDS pipe ~1100cy < MFMA 2066cy).
// Per-acc (kt,kk) accumulation order unchanged -> bit-identical GEMM.

typedef __bf16 bf16x8 __attribute__((ext_vector_type(8)));
typedef float f32x4 __attribute__((ext_vector_type(4)));

struct alignas(16) BF8 { __bf16 h[8]; };
struct alignas(8)  BF4 { __bf16 h[4]; };

typedef const __attribute__((address_space(1))) void glb_void;
typedef __attribute__((address_space(3))) void lds_void;

#define SEQ 2048
#define NB  32
#define HID 1024
#define MROWS (NB * SEQ)          // 65536
#define NKT 16                    // K tiles of 64

// branch-free exact-GELU via A&S 7.1.26 erf approximation (|eps| < 1.5e-7)
__device__ __forceinline__ float gelu_bf(float x) {
    float z  = 0.70710678118f * x;
    float az = fabsf(z);
    float t  = __builtin_amdgcn_rcpf(fmaf(0.3275911f, az, 1.0f));
    float poly = fmaf(fmaf(fmaf(fmaf(1.061405429f, t, -1.453152027f), t,
                         1.421413741f), t, -0.284496736f), t, 0.254829592f) * t;
    float ex = __expf(-az * az);
    float er = copysignf(fmaf(-poly, ex, 1.0f), z);
    return 0.5f * x * (1.0f + er);
}

// ---------------- init logits with b2 (FALLBACK path only) ----------------------
__global__ void sr_init_logits(float* __restrict__ logits, const float* __restrict__ b2) {
    int i = blockIdx.x * 256 + threadIdx.x;
    if (i < MROWS * 2) logits[i] = b2[i & 1];
}

// ---------------- W1 first half -> bf16 -----------------------------------------
__global__ void sr_conv_w1(const float* __restrict__ W1, __bf16* __restrict__ Bt) {
    int gid = blockIdx.x * 256 + threadIdx.x;
    int h = gid >> 8;
    int kb = (gid & 255) * 4;
    float4 v = *(const float4*)&W1[(size_t)h * 2048 + kb];
    BF4 o;
    o.h[0] = (__bf16)v.x; o.h[1] = (__bf16)v.y; o.h[2] = (__bf16)v.z; o.h[3] = (__bf16)v.w;
    *(BF4*)&Bt[(size_t)h * 1024 + kb] = o;
}

// ---------------- formula embedding: index-gather (labels scanned, not enc) -----
__global__ void sr_femb(const float* __restrict__ enc, const int* __restrict__ lab,
                        float* __restrict__ femb) {
    __shared__ int cnt;
    __shared__ int idl[64];                 // plenty: exactly 1 hit/sample by construction
    int b = blockIdx.x;
    int tid = threadIdx.x;
    if (tid == 0) cnt = 0;
    __syncthreads();
    for (int s = tid; s < SEQ; s += 256)
        if (lab[b * SEQ + s] == 2) {
            int p = atomicAdd(&cnt, 1);
            if (p < 64) idl[p] = s;
        }
    __syncthreads();
    float4 a = {0.f, 0.f, 0.f, 0.f};
    int n = cnt < 64 ? cnt : 64;
    for (int i = 0; i < n; ++i) {
        float4 v = *(const float4*)&enc[((size_t)b * SEQ + idl[i]) * HID + tid * 4];
        a.x += v.x; a.y += v.y; a.z += v.z; a.w += v.w;
    }
    *(float4*)&femb[b * HID + tid * 4] = a;
}

// ---------------- fc[b,h] = b1[h] + femb[b,:] . W1[h,1024:2048] -----------------
__global__ void sr_fc(const float* __restrict__ femb, const float* __restrict__ W1,
                      const float* __restrict__ b1, float* __restrict__ fcout) {
    int gw = (blockIdx.x * 256 + threadIdx.x) >> 6;
    int lane = threadIdx.x & 63;
    for (int i = 0; i < 16; ++i) {
        int d = gw * 16 + i;
        int b = d >> 10, h = d & 1023;
        const float* fe = femb + b * HID;
        const float* wr = W1 + (size_t)h * 2048 + 1024;
        float p = 0.f;
        #pragma unroll
        for (int t = 0; t < 16; ++t) {
            int k = lane + t * 64;
            p += fe[k] * wr[k];
        }
        #pragma unroll
        for (int off = 32; off; off >>= 1) p += __shfl_down(p, off);
        if (lane == 0) fcout[d] = p + b1[h];
    }
}

// ---------------- PRIMARY: 256^2 GEMM, A direct-from-enc (f32->bf16 in-reg) -----
__global__ __launch_bounds__(512, 2)
void sr_gemm15(const float* __restrict__ enc, const __bf16* __restrict__ Bt,
               const float* __restrict__ fc, const float* __restrict__ W2,
               float* __restrict__ partg) {
    // 65536 B: loop uses LB[2] (2 x 32 KB); epilogue reuses as red[512][20] (40 KB)
    __shared__ __align__(16) unsigned char smem[65536];
    __bf16* LBb = (__bf16*)smem;                    // LB[buf] = LBb + buf*16384
    float*  red = (float*)smem;                     // [512][20] f32 epilogue scratch

    int bid = blockIdx.x;
    int lgc = (bid & 7) * 128 + (bid >> 3);         // XCD-bijective (1024 % 8 == 0)
    int pm = lgc >> 2, pn = lgc & 3;
    const int row0 = pm * 256, col0 = pn * 256;

    int tid = threadIdx.x;
    int wid = tid >> 6, lane = tid & 63;
    int l15 = lane & 15, lq = lane >> 4;

    f32x4 acc[2][16] = {};                          // [m][n]: 32 rows x 256 cols / wave
    float4 a32[2][2][2];                            // [m][kk][half] in-flight A (f32)
    bf16x8 afb[2][2];                               // current-tile A frags

    // this lane's two A row pointers (m = 0,1) + MFMA k-slice offset
    const float* arow0 = enc + (size_t)(row0 + wid * 32 + l15) * HID + lq * 8;
    const float* arow1 = arow0 + 16 * HID;

    #define LOAD_A(kt) do {                                                       \
        const float* s0 = arow0 + (kt) * 64;                                      \
        const float* s1 = arow1 + (kt) * 64;                                      \
        a32[0][0][0] = *(const float4*)s0;                                        \
        a32[0][0][1] = *(const float4*)(s0 + 4);                                  \
        a32[0][1][0] = *(const float4*)(s0 + 32);                                 \
        a32[0][1][1] = *(const float4*)(s0 + 36);                                 \
        a32[1][0][0] = *(const float4*)s1;                                        \
        a32[1][0][1] = *(const float4*)(s1 + 4);                                  \
        a32[1][1][0] = *(const float4*)(s1 + 32);                                 \
        a32[1][1][1] = *(const float4*)(s1 + 36);                                 \
    } while (0)

    #define CVT_A() do {                                                          \
        _Pragma("unroll")                                                         \
        for (int m = 0; m < 2; ++m)                                               \
            _Pragma("unroll")                                                     \
            for (int kk = 0; kk < 2; ++kk) {                                      \
                BF8 t;                                                            \
                t.h[0] = (__bf16)a32[m][kk][0].x; t.h[1] = (__bf16)a32[m][kk][0].y;\
                t.h[2] = (__bf16)a32[m][kk][0].z; t.h[3] = (__bf16)a32[m][kk][0].w;\
                t.h[4] = (__bf16)a32[m][kk][1].x; t.h[5] = (__bf16)a32[m][kk][1].y;\
                t.h[6] = (__bf16)a32[m][kk][1].z; t.h[7] = (__bf16)a32[m][kk][1].w;\
                afb[m][kk] = *(bf16x8*)&t;                                        \
            }                                                                     \
    } while (0)

    #define STAGE_B(buf, kt) do {                                                 \
        _Pragma("unroll")                                                         \
        for (int i = 0; i < 4; ++i) {                                             \
            int q = i * 512 + tid;                                                \
            int r = q >> 3, c = q & 7;                                            \
            int sc = (c ^ (r & 7)) * 8 + (kt) * 64;                               \
            __builtin_amdgcn_global_load_lds(                                     \
                (glb_void*)(Bt + (size_t)(col0 + r) * HID + sc),                  \
                (lds_void*)(LBb + (buf) * 16384 + q * 8), 16, 0, 0);              \
        }                                                                         \
    } while (0)

    // prologue: A(0) into regs, B(0) into LDS; barrier drains both (per-wave vmcnt)
    LOAD_A(0);
    STAGE_B(0, 0);
    __syncthreads();

    int cur = 0;
    for (int kt = 0; kt < NKT; ++kt) {
        CVT_A();                        // a32 certified by last barrier's drain
        int ktn = (kt + 1 < NKT) ? kt + 1 : NKT - 1;
        LOAD_A(ktn);                    // prefetch (WAR on a32 is safe: cvt reads
                                        // precede these issues in program order)
        if (kt + 1 < NKT) STAGE_B(cur ^ 1, kt + 1);

        const __bf16* LBc = LBb + cur * 16384;
        #pragma unroll
        for (int n = 0; n < 16; ++n) {
            int r = n * 16 + l15;
            bf16x8 b0 = *(const bf16x8*)&LBc[r * 64 + ((lq ^ (r & 7)) * 8)];
            bf16x8 b1 = *(const bf16x8*)&LBc[r * 64 + (((4 + lq) ^ (r & 7)) * 8)];
            #pragma unroll
            for (int m = 0; m < 2; ++m) {
                acc[m][n] = __builtin_amdgcn_mfma_f32_16x16x32_bf16(
                    afb[m][0], b0, acc[m][n], 0, 0, 0);
                acc[m][n] = __builtin_amdgcn_mfma_f32_16x16x32_bf16(
                    afb[m][1], b1, acc[m][n], 0, 0, 0);
            }
        }
        __syncthreads();    // drains vmcnt (A prefetch + B DMA) + fences LB swap
        cur ^= 1;
    }
    #undef LOAD_A
    #undef CVT_A
    #undef STAGE_B

    // ---- epilogue: gelu+W2, n-sum in-thread, 16-wide LDS transpose, final sum --
    int b = row0 >> 11;
    float p[2][4][2] = {};              // [m][j][class]
    #pragma unroll
    for (int n = 0; n < 16; ++n) {
        int h = col0 + n * 16 + l15;
        float fcv = fc[b * HID + h];
        float wa = W2[h], wb = W2[HID + h];
        #pragma unroll
        for (int m = 0; m < 2; ++m)
            #pragma unroll
            for (int j = 0; j < 4; ++j) {
                float g = gelu_bf(acc[m][n][j] + fcv);
                p[m][j][0] = fmaf(g, wa, p[m][j][0]);
                p[m][j][1] = fmaf(g, wb, p[m][j][1]);
            }
    }
    // last loop iteration ended with __syncthreads -> LB reads complete, red safe
    #pragma unroll
    for (int m = 0; m < 2; ++m)
        #pragma unroll
        for (int j = 0; j < 4; ++j) {
            int rloc = wid * 32 + m * 16 + lq * 4 + j;
            red[(rloc * 2 + 0) * 20 + l15] = p[m][j][0];
            red[(rloc * 2 + 1) * 20 + l15] = p[m][j][1];
        }
    __syncthreads();
    {   // one (row, class) per thread: sum 16 partials via 4 aligned b128 reads
        const f32x4* rp = (const f32x4*)&red[tid * 20];
        f32x4 sv = rp[0] + rp[1] + rp[2] + rp[3];
        float s = sv[0] + sv[1] + sv[2] + sv[3];
        int row = tid >> 1, c = tid & 1;
        partg[((size_t)pn * MROWS + row0 + row) * 2 + c] = s;
    }
}

// ---------------- FALLBACK GEMM (atomics path, used only if ws too small) -------
__global__ __launch_bounds__(256, 2)
void sr_gemm_fused(const float* __restrict__ enc, const __bf16* __restrict__ Bt,
                   const float* __restrict__ fc, const float* __restrict__ W2,
                   float* __restrict__ logits) {
    __shared__ __bf16 As[128 * 64];
    __shared__ __bf16 Bs[128 * 64];

    int bid = blockIdx.x;
    int logical = (bid & 7) * 512 + (bid >> 3);
    int pm = logical >> 3;
    int pn = logical & 7;

    int tid = threadIdx.x;
    int wid = tid >> 6, lane = tid & 63;
    int wm = wid >> 1, wn = wid & 1;

    const int row0 = pm * 128;
    const int col0 = pn * 128;

    f32x4 acc[4][4] = {};

    for (int kt = 0; kt < 16; ++kt) {
        int k0 = kt * 64;
        #pragma unroll
        for (int i = 0; i < 4; ++i) {
            int q = i * 256 + tid;
            int r = q >> 3;
            int cb = (q & 7) * 8;
            const __bf16* src = Bt + (size_t)(col0 + r) * 1024 + k0 + cb;
            __builtin_amdgcn_global_load_lds((glb_void*)src, (lds_void*)&Bs[q * 8], 16, 0, 0);
        }
        #pragma unroll
        for (int pp = 0; pp < 4; ++pp) {
            int e = pp * 2048 + tid * 8;
            int r = e >> 6, c = e & 63;
            const float* src = enc + (size_t)(row0 + r) * 1024 + k0 + c;
            float4 f0 = *(const float4*)src;
            float4 f1 = *(const float4*)(src + 4);
            BF8 t;
            t.h[0] = (__bf16)f0.x; t.h[1] = (__bf16)f0.y;
            t.h[2] = (__bf16)f0.z; t.h[3] = (__bf16)f0.w;
            t.h[4] = (__bf16)f1.x; t.h[5] = (__bf16)f1.y;
            t.h[6] = (__bf16)f1.z; t.h[7] = (__bf16)f1.w;
            *(BF8*)&As[r * 64 + c] = t;
        }
        __syncthreads();
        int lrow = lane & 15;
        int ak = (lane >> 4) * 8;
        #pragma unroll
        for (int kk = 0; kk < 2; ++kk) {
            bf16x8 a[4], b[4];
            #pragma unroll
            for (int m = 0; m < 4; ++m)
                a[m] = *(const bf16x8*)&As[(wm * 64 + m * 16 + lrow) * 64 + kk * 32 + ak];
            #pragma unroll
            for (int n = 0; n < 4; ++n)
                b[n] = *(const bf16x8*)&Bs[(wn * 64 + n * 16 + lrow) * 64 + kk * 32 + ak];
            #pragma unroll
            for (int m = 0; m < 4; ++m)
                #pragma unroll
                for (int n = 0; n < 4; ++n)
                    acc[m][n] = __builtin_amdgcn_mfma_f32_16x16x32_bf16(a[m], b[n], acc[m][n], 0, 0, 0);
        }
        __syncthreads();
    }

    int bidx = row0 >> 11;
    float fcv[4], w2a[4], w2b[4];
    #pragma unroll
    for (int n = 0; n < 4; ++n) {
        int h = col0 + wn * 64 + n * 16 + (lane & 15);
        fcv[n] = fc[bidx * HID + h];
        w2a[n] = W2[h];
        w2b[n] = W2[HID + h];
    }
    #pragma unroll
    for (int m = 0; m < 4; ++m) {
        int rbase = row0 + wm * 64 + m * 16 + (lane >> 4) * 4;
        #pragma unroll
        for (int j = 0; j < 4; ++j) {
            float p0 = 0.f, p1 = 0.f;
            #pragma unroll
            for (int n = 0; n < 4; ++n) {
                float g = gelu_bf(acc[m][n][j] + fcv[n]);
                p0 += g * w2a[n];
                p1 += g * w2b[n];
            }
            #pragma unroll
            for (int off = 1; off < 16; off <<= 1) {
                p0 += __shfl_xor(p0, off);
                p1 += __shfl_xor(p1, off);
            }
            if ((lane & 15) == 0) {
                int rg = rbase + j;
                atomicAdd(&logits[rg * 2 + 0], p0);
                atomicAdd(&logits[rg * 2 + 1], p1);
            }
        }
    }
}

// ---------------- loss from partials: logits = b2 + sum_pn partg; CE ------------
__global__ void sr_loss_pg(const int* __restrict__ lab, const float* __restrict__ partg,
                           const float* __restrict__ b2, float* __restrict__ logits,
                           float* __restrict__ mask_out, float* __restrict__ sl,
                           float* __restrict__ validv) {
    int b = blockIdx.x;
    int tid = threadIdx.x;
    float b20 = b2[0], b21 = b2[1];
    float lsum = 0.f; int lcnt = 0;
    for (int s = tid; s < SEQ; s += 256) {
        size_t row = (size_t)b * SEQ + s;
        float l0 = b20, l1 = b21;
        #pragma unroll
        for (int q = 0; q < 4; ++q) {
            l0 += partg[((size_t)q * MROWS + row) * 2 + 0];
            l1 += partg[((size_t)q * MROWS + row) * 2 + 1];
        }
        logits[row * 2 + 0] = l0;
        logits[row * 2 + 1] = l1;
        int l = lab[row];
        bool hdr = (l == 0) || (l == 1);
        mask_out[row] = hdr ? 1.0f : 0.0f;
        if (hdr) {
            float mx = fmaxf(l0, l1);
            float lse = mx + logf(expf(l0 - mx) + expf(l1 - mx));
            lsum += lse - (l == 0 ? l0 : l1);
            lcnt++;
        }
    }
    #pragma unroll
    for (int off = 32; off; off >>= 1) {
        lsum += __shfl_down(lsum, off);
        lcnt += __shfl_down(lcnt, off);
    }
    __shared__ float wsum[4];
    __shared__ int wcnt[4];
    int wid = tid >> 6, lane = tid & 63;
    if (lane == 0) { wsum[wid] = lsum; wcnt[wid] = lcnt; }
    __syncthreads();
    if (tid == 0) {
        float S = wsum[0] + wsum[1] + wsum[2] + wsum[3];
        int C = wcnt[0] + wcnt[1] + wcnt[2] + wcnt[3];
        sl[b] = (C > 0) ? S / (float)C : 0.0f;
        validv[b] = (C > 0) ? 1.0f : 0.0f;
    }
}

// ---------------- loss reading logits directly (FALLBACK path) ------------------
__global__ void sr_loss(const int* __restrict__ lab, const float* __restrict__ logits,
                        float* __restrict__ mask_out, float* __restrict__ sl,
                        float* __restrict__ validv) {
    int b = blockIdx.x;
    int tid = threadIdx.x;
    float lsum = 0.f; int lcnt = 0;
    for (int s = tid; s < SEQ; s += 256) {
        int l = lab[b * SEQ + s];
        bool hdr = (l == 0) || (l == 1);
        mask_out[b * SEQ + s] = hdr ? 1.0f : 0.0f;
        if (hdr) {
            float l0 = logits[(b * SEQ + s) * 2];
            float l1 = logits[(b * SEQ + s) * 2 + 1];
            float mx = fmaxf(l0, l1);
            float lse = mx + logf(expf(l0 - mx) + expf(l1 - mx));
            lsum += lse - (l == 0 ? l0 : l1);
            lcnt++;
        }
    }
    #pragma unroll
    for (int off = 32; off; off >>= 1) {
        lsum += __shfl_down(lsum, off);
        lcnt += __shfl_down(lcnt, off);
    }
    __shared__ float wsum[4];
    __shared__ int wcnt[4];
    int wid = tid >> 6, lane = tid & 63;
    if (lane == 0) { wsum[wid] = lsum; wcnt[wid] = lcnt; }
    __syncthreads();
    if (tid == 0) {
        float S = wsum[0] + wsum[1] + wsum[2] + wsum[3];
        int C = wcnt[0] + wcnt[1] + wcnt[2] + wcnt[3];
        sl[b] = (C > 0) ? S / (float)C : 0.0f;
        validv[b] = (C > 0) ? 1.0f : 0.0f;
    }
}

__global__ void sr_final(const float* __restrict__ sl, const float* __restrict__ validv,
                         float* __restrict__ out) {
    if (threadIdx.x == 0) {
        float s = 0.f, v = 0.f;
        for (int b = 0; b < NB; ++b) { s += sl[b]; v += validv[b]; }
        out[0] = s / (v + 1e-6f);
    }
}

extern "C" void kernel_launch(void* const* d_in, const int* in_sizes, int n_in,
                              void* d_out, int out_size, void* d_ws, size_t ws_size,
                              hipStream_t stream) {
    const float* enc = (const float*)d_in[0];
    const int*   lab = (const int*)d_in[1];
    const float* W1  = (const float*)d_in[2];
    const float* b1  = (const float*)d_in[3];
    const float* W2  = (const float*)d_in[4];
    const float* b2  = (const float*)d_in[5];

    float* out     = (float*)d_out;
    float* loss    = out;
    float* logits  = out + 1;
    float* maskout = out + 1 + MROWS * 2;

    float* ws     = (float*)d_ws;
    float* femb   = ws;                            // 32768 f32
    float* fc     = ws + 32768;                    // 32768 f32
    float* sl     = ws + 65536;                    // 32
    float* validv = ws + 65568;                    // 32
    float* partg  = ws + 65600;                    // 524288 f32 (2 MB)
    __bf16* Bt    = (__bf16*)(ws + 65600 + 2 * 524288);  // 2 MB

    const size_t need = (65600u + 2u * 524288u) * 4u + (size_t)HID * HID * 2u;

    sr_conv_w1<<<1024, 256, 0, stream>>>(W1, Bt);
    sr_femb<<<32, 256, 0, stream>>>(enc, lab, femb);
    sr_fc<<<512, 256, 0, stream>>>(femb, W1, b1, fc);

    if (ws_size >= need) {
        sr_gemm15<<<1024, 512, 0, stream>>>(enc, Bt, fc, W2, partg);
        sr_loss_pg<<<32, 256, 0, stream>>>(lab, partg, b2, logits, maskout, sl, validv);
    } else {
        sr_init_logits<<<512, 256, 0, stream>>>(logits, b2);
        sr_gemm_fused<<<4096, 256, 0, stream>>>(enc, Bt, fc, W2, logits);
        sr_loss<<<32, 256, 0, stream>>>(lab, logits, maskout, sl, validv);
    }

    sr_final<<<1, 64, 0, stream>>>(sl, validv, loss);
}

// Round 7
// 261.308 us; speedup vs baseline: 1.0701x; 1.0701x over previous
//
#include <hip/hip_runtime.h>
#include <math.h>

// Problem: B=32, S=2048, H=1024
//   d_out (float): [0] loss | [1..131073) logits (32,2048,2) | [131073..196609) header_mask
//
// R16: corrected faithful port of the m201 8-phase template (R10's port had a
// prologue under-certification race — vmcnt(6) after 7 half-stages certifies
// only the oldest 1, not tile-0's 4 halves — plus inconsistent A/B prefetch
// depths). Clean derivation: 1 half-tile staged per phase, stage lags the
// slot's last read by one phase: P1->A(t+1,h1), P2->A(t+2,h0), P3->B(t+2,h0),
// P4->B(t+2,h1); vmcnt(6) at P4 certifies exactly through tile t+1 (3 stages
// x 2 loads stay in flight, never drained in-loop). Prologue stages 7 halves,
// vmcnt(6) certifies the oldest 8 loads = tile 0. Per-wave vmcnt + P4 barrier
// => globally sound. Byte-identical LDS layout/swizzle and per-acc (kt,kk)
// order vs R9 -> bit-identical results. A stays on global_load_lds (R11/R15:
// any other A path regresses); conv_enc stays (BW-floor ~60us).

typedef __bf16 bf16x8 __attribute__((ext_vector_type(8)));
typedef float f32x4 __attribute__((ext_vector_type(4)));

struct alignas(16) BF8 { __bf16 h[8]; };
struct alignas(8)  BF4 { __bf16 h[4]; };

typedef const __attribute__((address_space(1))) void glb_void;
typedef __attribute__((address_space(3))) void lds_void;

#define SEQ 2048
#define NB  32
#define HID 1024
#define MROWS (NB * SEQ)          // 65536
#define NKT 16                    // K tiles of 64

// branch-free exact-GELU via A&S 7.1.26 erf approximation (|eps| < 1.5e-7)
__device__ __forceinline__ float gelu_bf(float x) {
    float z  = 0.70710678118f * x;
    float az = fabsf(z);
    float t  = __builtin_amdgcn_rcpf(fmaf(0.3275911f, az, 1.0f));
    float poly = fmaf(fmaf(fmaf(fmaf(1.061405429f, t, -1.453152027f), t,
                         1.421413741f), t, -0.284496736f), t, 0.254829592f) * t;
    float ex = __expf(-az * az);
    float er = copysignf(fmaf(-poly, ex, 1.0f), z);
    return 0.5f * x * (1.0f + er);
}

// ---------------- init logits with b2 (FALLBACK path only) ----------------------
__global__ void sr_init_logits(float* __restrict__ logits, const float* __restrict__ b2) {
    int i = blockIdx.x * 256 + threadIdx.x;
    if (i < MROWS * 2) logits[i] = b2[i & 1];
}

// ---------------- W1 first half -> bf16 -----------------------------------------
__global__ void sr_conv_w1(const float* __restrict__ W1, __bf16* __restrict__ Bt) {
    int gid = blockIdx.x * 256 + threadIdx.x;
    int h = gid >> 8;
    int kb = (gid & 255) * 4;
    float4 v = *(const float4*)&W1[(size_t)h * 2048 + kb];
    BF4 o;
    o.h[0] = (__bf16)v.x; o.h[1] = (__bf16)v.y; o.h[2] = (__bf16)v.z; o.h[3] = (__bf16)v.w;
    *(BF4*)&Bt[(size_t)h * 1024 + kb] = o;
}

// ---------------- enc f32 -> bf16 (Ab) ------------------------------------------
__global__ void sr_conv_enc(const float* __restrict__ enc, __bf16* __restrict__ Ab) {
    size_t i = ((size_t)blockIdx.x * 256 + threadIdx.x) * 8;
    float4 v0 = *(const float4*)&enc[i];
    float4 v1 = *(const float4*)&enc[i + 4];
    BF8 t;
    t.h[0] = (__bf16)v0.x; t.h[1] = (__bf16)v0.y;
    t.h[2] = (__bf16)v0.z; t.h[3] = (__bf16)v0.w;
    t.h[4] = (__bf16)v1.x; t.h[5] = (__bf16)v1.y;
    t.h[6] = (__bf16)v1.z; t.h[7] = (__bf16)v1.w;
    *(BF8*)&Ab[i] = t;
}

// ---------------- formula embedding: index-gather (labels scanned, not enc) -----
__global__ void sr_femb(const float* __restrict__ enc, const int* __restrict__ lab,
                        float* __restrict__ femb) {
    __shared__ int cnt;
    __shared__ int idl[64];                 // plenty: exactly 1 hit/sample by construction
    int b = blockIdx.x;
    int tid = threadIdx.x;
    if (tid == 0) cnt = 0;
    __syncthreads();
    for (int s = tid; s < SEQ; s += 256)
        if (lab[b * SEQ + s] == 2) {
            int p = atomicAdd(&cnt, 1);
            if (p < 64) idl[p] = s;
        }
    __syncthreads();
    float4 a = {0.f, 0.f, 0.f, 0.f};
    int n = cnt < 64 ? cnt : 64;
    for (int i = 0; i < n; ++i) {
        float4 v = *(const float4*)&enc[((size_t)b * SEQ + idl[i]) * HID + tid * 4];
        a.x += v.x; a.y += v.y; a.z += v.z; a.w += v.w;
    }
    *(float4*)&femb[b * HID + tid * 4] = a;
}

// ---------------- fc[b,h] = b1[h] + femb[b,:] . W1[h,1024:2048] -----------------
__global__ void sr_fc(const float* __restrict__ femb, const float* __restrict__ W1,
                      const float* __restrict__ b1, float* __restrict__ fcout) {
    int gw = (blockIdx.x * 256 + threadIdx.x) >> 6;
    int lane = threadIdx.x & 63;
    for (int i = 0; i < 16; ++i) {
        int d = gw * 16 + i;
        int b = d >> 10, h = d & 1023;
        const float* fe = femb + b * HID;
        const float* wr = W1 + (size_t)h * 2048 + 1024;
        float p = 0.f;
        #pragma unroll
        for (int t = 0; t < 16; ++t) {
            int k = lane + t * 64;
            p += fe[k] * wr[k];
        }
        #pragma unroll
        for (int off = 32; off; off >>= 1) p += __shfl_down(p, off);
        if (lane == 0) fcout[d] = p + b1[h];
    }
}

// ---------------- PRIMARY: 256^2 8-phase GEMM (m201 template, corrected) --------
__global__ __launch_bounds__(512, 2)
void sr_gemm16(const __bf16* __restrict__ Ab, const __bf16* __restrict__ Bt,
               const float* __restrict__ fc, const float* __restrict__ W2,
               float* __restrict__ partg) {
    // 139264 B: loop uses first 131072 as 4 half-slots (16 KB) per matrix;
    // epilogue reuses all as red[]
    __shared__ __align__(16) unsigned char smem[139264];
    __bf16* LAb = (__bf16*)smem;                    // A half-slot s: LAb + s*8192
    __bf16* LBb = (__bf16*)(smem + 65536);          // B half-slot s: LBb + s*8192
    float*  red = (float*)smem;                     // [256*2][68] f32 epilogue scratch

    int bid = blockIdx.x;
    int lgc = (bid & 7) * 128 + (bid >> 3);         // XCD-bijective (1024 % 8 == 0)
    int pm = lgc >> 2, pn = lgc & 3;
    const int row0 = pm * 256, col0 = pn * 256;

    int tid = threadIdx.x;
    int wid = tid >> 6, lane = tid & 63;
    int wr = wid >> 2, wc = wid & 3;
    int l15 = lane & 15, lq = lane >> 4;

    f32x4 acc[2][2][4][2] = {};
    bf16x8 af[4][2];            // current-qa A frags (live P1-P2 for qa0, P3-P4 qa1)
    bf16x8 bfr[2][2][2];        // both B halves' frags (h0: P1->P3, h1: P2->P4)

    // stage one 128x64 half-tile (2 x global_load_lds dwordx4 per thread)
    #define STG_H(DSTBASE, SRC, ROWB, KT, HH) do {                                \
        _Pragma("unroll")                                                         \
        for (int i = 0; i < 2; ++i) {                                             \
            int q = i * 512 + tid;                                                \
            int r = q >> 3, c = q & 7;                                            \
            int sc = (c ^ (r & 7)) * 8 + (KT) * 64;                               \
            __builtin_amdgcn_global_load_lds(                                     \
                (glb_void*)((SRC) + (size_t)((ROWB) + (HH) * 128 + r) * HID + sc),\
                (lds_void*)((DSTBASE) + q * 8), 16, 0, 0);                        \
        }                                                                         \
    } while (0)

    #define RD_A(HB)                                                              \
        _Pragma("unroll") for (int m = 0; m < 4; ++m)                             \
        _Pragma("unroll") for (int kk = 0; kk < 2; ++kk) {                        \
            int r = wr * 64 + m * 16 + l15;                                       \
            af[m][kk] = *(const bf16x8*)&(HB)[r * 64 + (((kk*4+lq) ^ (r&7)) * 8)];\
        }

    #define RD_B(QB, HB)                                                          \
        _Pragma("unroll") for (int n = 0; n < 2; ++n)                             \
        _Pragma("unroll") for (int kk = 0; kk < 2; ++kk) {                        \
            int r = wc * 32 + n * 16 + l15;                                       \
            bfr[QB][n][kk] = *(const bf16x8*)&(HB)[r * 64 + (((kk*4+lq) ^ (r&7)) * 8)];\
        }

    #define MM(QA, QB)                                                            \
        _Pragma("unroll") for (int m = 0; m < 4; ++m)                             \
        _Pragma("unroll") for (int n = 0; n < 2; ++n)                             \
        _Pragma("unroll") for (int kk = 0; kk < 2; ++kk)                          \
            acc[QA][QB][m][n] = __builtin_amdgcn_mfma_f32_16x16x32_bf16(          \
                af[m][kk], bfr[QB][n][kk], acc[QA][QB][m][n], 0, 0, 0);

    #define BAR()   do { __builtin_amdgcn_s_barrier();                            \
                         asm volatile("" ::: "memory"); } while (0)
    #define LGKM0() do { asm volatile("s_waitcnt lgkmcnt(0)" ::: "memory");       \
                         __builtin_amdgcn_sched_barrier(0); } while (0)

    // One K-tile = 4 phases. PAR = T&1 selects the slot pair {PAR*2, PAR*2+1}.
    // Stage rotation (each slot staged one phase after its last read):
    //   P1 -> A(T+1,h1) into slot A[(PAR^1)*2+1]   (freed at P3 of tile T-1)
    //   P2 -> A(T+2,h0) into slot A[PAR*2+0]       (freed at P1 of tile T)
    //   P3 -> B(T+2,h0) into slot B[PAR*2+0]       (freed at P1 of tile T)
    //   P4 -> B(T+2,h1) into slot B[PAR*2+1]       (freed at P2 of tile T)
    // vmcnt(6) at P4 certifies through P1's stage = ALL of tile T+1; the 3
    // stages of P2-P4 (6 loads) stay in flight across the barrier.
    #define KTILE(PAR, T)                                                         \
    {                                                                             \
        int tn1 = (T) + 1 < NKT ? (T) + 1 : NKT - 1;                              \
        int tn2 = (T) + 2 < NKT ? (T) + 2 : NKT - 1;                              \
        const __bf16* A0 = LAb + ((PAR) * 2 + 0) * 8192;                          \
        const __bf16* A1 = LAb + ((PAR) * 2 + 1) * 8192;                          \
        const __bf16* B0 = LBb + ((PAR) * 2 + 0) * 8192;                          \
        const __bf16* B1 = LBb + ((PAR) * 2 + 1) * 8192;                          \
        /* P1 */                                                                  \
        RD_A(A0);                                                                 \
        RD_B(0, B0);                                                              \
        STG_H(LAb + (((PAR) ^ 1) * 2 + 1) * 8192, Ab, row0, tn1, 1);              \
        BAR(); LGKM0();                                                           \
        __builtin_amdgcn_s_setprio(1);                                            \
        MM(0, 0);                                                                 \
        __builtin_amdgcn_s_setprio(0);                                            \
        BAR();                                                                    \
        /* P2 */                                                                  \
        RD_B(1, B1);                                                              \
        STG_H((__bf16*)A0, Ab, row0, tn2, 0);                                     \
        BAR(); LGKM0();                                                           \
        __builtin_amdgcn_s_setprio(1);                                            \
        MM(0, 1);                                                                 \
        __builtin_amdgcn_s_setprio(0);                                            \
        BAR();                                                                    \
        /* P3 */                                                                  \
        RD_A(A1);                                                                 \
        STG_H((__bf16*)B0, Bt, col0, tn2, 0);                                     \
        BAR(); LGKM0();                                                           \
        __builtin_amdgcn_s_setprio(1);                                            \
        MM(1, 0);                                                                 \
        __builtin_amdgcn_s_setprio(0);                                            \
        BAR();                                                                    \
        /* P4 */                                                                  \
        STG_H((__bf16*)B1, Bt, col0, tn2, 1);                                     \
        BAR();                                                                    \
        __builtin_amdgcn_s_setprio(1);                                            \
        MM(1, 1);                                                                 \
        __builtin_amdgcn_s_setprio(0);                                            \
        asm volatile("s_waitcnt vmcnt(6)" ::: "memory");                          \
        __builtin_amdgcn_sched_barrier(0);                                        \
        BAR();                                                                    \
    }

    // prologue: 7 halves (14 loads); vmcnt(6) certifies the oldest 8 = tile 0.
    // In-flight set entering tile 0: {A(1,0), B(1,0), B(1,1)} = steady state.
    STG_H(LAb + 0 * 8192, Ab, row0, 0, 0);      // A(0,h0) -> slot A0
    STG_H(LBb + 0 * 8192, Bt, col0, 0, 0);      // B(0,h0) -> slot B0
    STG_H(LBb + 1 * 8192, Bt, col0, 0, 1);      // B(0,h1) -> slot B1
    STG_H(LAb + 1 * 8192, Ab, row0, 0, 1);      // A(0,h1) -> slot A1
    STG_H(LAb + 2 * 8192, Ab, row0, 1, 0);      // A(1,h0) -> slot A2
    STG_H(LBb + 2 * 8192, Bt, col0, 1, 0);      // B(1,h0) -> slot B2
    STG_H(LBb + 3 * 8192, Bt, col0, 1, 1);      // B(1,h1) -> slot B3
    asm volatile("s_waitcnt vmcnt(6)" ::: "memory");
    __builtin_amdgcn_sched_barrier(0);
    BAR();

    for (int u = 0; u < 8; ++u) {
        KTILE(0, 2 * u);
        KTILE(1, 2 * u + 1);
    }

    #undef KTILE
    #undef STG_H
    #undef RD_A
    #undef RD_B
    #undef MM
    #undef BAR
    #undef LGKM0

    // drain the clamped tail stages (dead slots) before red[] aliases the rings
    __syncthreads();

    // ---- epilogue: per-lane gelu+W2 partials -> LDS transpose -> tree-free sum --
    int b = row0 >> 11;
    float fcv[2][2], w2a[2][2], w2b[2][2];
    #pragma unroll
    for (int qb = 0; qb < 2; ++qb)
        #pragma unroll
        for (int n = 0; n < 2; ++n) {
            int h = col0 + qb * 128 + wc * 32 + n * 16 + l15;
            fcv[qb][n] = fc[b * HID + h];
            w2a[qb][n] = W2[h];
            w2b[qb][n] = W2[HID + h];
        }
    int e = wc * 16 + l15;                  // 0..63: which h-subgroup this lane covers
    #pragma unroll
    for (int qa = 0; qa < 2; ++qa)
        #pragma unroll
        for (int m = 0; m < 4; ++m)
            #pragma unroll
            for (int j = 0; j < 4; ++j) {
                int rloc = qa * 128 + wr * 64 + m * 16 + lq * 4 + j;
                float p0 = 0.f, p1 = 0.f;
                #pragma unroll
                for (int qb = 0; qb < 2; ++qb)
                    #pragma unroll
                    for (int n = 0; n < 2; ++n) {
                        float g = gelu_bf(acc[qa][qb][m][n][j] + fcv[qb][n]);
                        p0 += g * w2a[qb][n];
                        p1 += g * w2b[qb][n];
                    }
                red[(rloc * 2 + 0) * 68 + e] = p0;
                red[(rloc * 2 + 1) * 68 + e] = p1;
            }
    __syncthreads();
    {   // one (row, class) per thread: sum 64 partials via 16 aligned b128 reads
        const f32x4* rp = (const f32x4*)&red[tid * 68];
        f32x4 sv = {0.f, 0.f, 0.f, 0.f};
        #pragma unroll
        for (int i = 0; i < 16; ++i) sv += rp[i];
        float s = sv[0] + sv[1] + sv[2] + sv[3];
        int row = tid >> 1, c = tid & 1;
        partg[((size_t)pn * MROWS + row0 + row) * 2 + c] = s;
    }
}

// ---------------- FALLBACK GEMM (atomics path, used only if ws too small) -------
__global__ __launch_bounds__(256, 2)
void sr_gemm_fused(const float* __restrict__ enc, const __bf16* __restrict__ Bt,
                   const float* __restrict__ fc, const float* __restrict__ W2,
                   float* __restrict__ logits) {
    __shared__ __bf16 As[128 * 64];
    __shared__ __bf16 Bs[128 * 64];

    int bid = blockIdx.x;
    int logical = (bid & 7) * 512 + (bid >> 3);
    int pm = logical >> 3;
    int pn = logical & 7;

    int tid = threadIdx.x;
    int wid = tid >> 6, lane = tid & 63;
    int wm = wid >> 1, wn = wid & 1;

    const int row0 = pm * 128;
    const int col0 = pn * 128;

    f32x4 acc[4][4] = {};

    for (int kt = 0; kt < 16; ++kt) {
        int k0 = kt * 64;
        #pragma unroll
        for (int i = 0; i < 4; ++i) {
            int q = i * 256 + tid;
            int r = q >> 3;
            int cb = (q & 7) * 8;
            const __bf16* src = Bt + (size_t)(col0 + r) * 1024 + k0 + cb;
            __builtin_amdgcn_global_load_lds((glb_void*)src, (lds_void*)&Bs[q * 8], 16, 0, 0);
        }
        #pragma unroll
        for (int pp = 0; pp < 4; ++pp) {
            int e = pp * 2048 + tid * 8;
            int r = e >> 6, c = e & 63;
            const float* src = enc + (size_t)(row0 + r) * 1024 + k0 + c;
            float4 f0 = *(const float4*)src;
            float4 f1 = *(const float4*)(src + 4);
            BF8 t;
            t.h[0] = (__bf16)f0.x; t.h[1] = (__bf16)f0.y;
            t.h[2] = (__bf16)f0.z; t.h[3] = (__bf16)f0.w;
            t.h[4] = (__bf16)f1.x; t.h[5] = (__bf16)f1.y;
            t.h[6] = (__bf16)f1.z; t.h[7] = (__bf16)f1.w;
            *(BF8*)&As[r * 64 + c] = t;
        }
        __syncthreads();
        int lrow = lane & 15;
        int ak = (lane >> 4) * 8;
        #pragma unroll
        for (int kk = 0; kk < 2; ++kk) {
            bf16x8 a[4], b[4];
            #pragma unroll
            for (int m = 0; m < 4; ++m)
                a[m] = *(const bf16x8*)&As[(wm * 64 + m * 16 + lrow) * 64 + kk * 32 + ak];
            #pragma unroll
            for (int n = 0; n < 4; ++n)
                b[n] = *(const bf16x8*)&Bs[(wn * 64 + n * 16 + lrow) * 64 + kk * 32 + ak];
            #pragma unroll
            for (int m = 0; m < 4; ++m)
                #pragma unroll
                for (int n = 0; n < 4; ++n)
                    acc[m][n] = __builtin_amdgcn_mfma_f32_16x16x32_bf16(a[m], b[n], acc[m][n], 0, 0, 0);
        }
        __syncthreads();
    }

    int bidx = row0 >> 11;
    float fcv[4], w2a[4], w2b[4];
    #pragma unroll
    for (int n = 0; n < 4; ++n) {
        int h = col0 + wn * 64 + n * 16 + (lane & 15);
        fcv[n] = fc[bidx * HID + h];
        w2a[n] = W2[h];
        w2b[n] = W2[HID + h];
    }
    #pragma unroll
    for (int m = 0; m < 4; ++m) {
        int rbase = row0 + wm * 64 + m * 16 + (lane >> 4) * 4;
        #pragma unroll
        for (int j = 0; j < 4; ++j) {
            float p0 = 0.f, p1 = 0.f;
            #pragma unroll
            for (int n = 0; n < 4; ++n) {
                float g = gelu_bf(acc[m][n][j] + fcv[n]);
                p0 += g * w2a[n];
                p1 += g * w2b[n];
            }
            #pragma unroll
            for (int off = 1; off < 16; off <<= 1) {
                p0 += __shfl_xor(p0, off);
                p1 += __shfl_xor(p1, off);
            }
            if ((lane & 15) == 0) {
                int rg = rbase + j;
                atomicAdd(&logits[rg * 2 + 0], p0);
                atomicAdd(&logits[rg * 2 + 1], p1);
            }
        }
    }
}

// ---------------- loss from partials: logits = b2 + sum_pn partg; CE ------------
__global__ void sr_loss_pg(const int* __restrict__ lab, const float* __restrict__ partg,
                           const float* __restrict__ b2, float* __restrict__ logits,
                           float* __restrict__ mask_out, float* __restrict__ sl,
                           float* __restrict__ validv) {
    int b = blockIdx.x;
    int tid = threadIdx.x;
    float b20 = b2[0], b21 = b2[1];
    float lsum = 0.f; int lcnt = 0;
    for (int s = tid; s < SEQ; s += 256) {
        size_t row = (size_t)b * SEQ + s;
        float l0 = b20, l1 = b21;
        #pragma unroll
        for (int q = 0; q < 4; ++q) {
            l0 += partg[((size_t)q * MROWS + row) * 2 + 0];
            l1 += partg[((size_t)q * MROWS + row) * 2 + 1];
        }
        logits[row * 2 + 0] = l0;
        logits[row * 2 + 1] = l1;
        int l = lab[row];
        bool hdr = (l == 0) || (l == 1);
        mask_out[row] = hdr ? 1.0f : 0.0f;
        if (hdr) {
            float mx = fmaxf(l0, l1);
            float lse = mx + logf(expf(l0 - mx) + expf(l1 - mx));
            lsum += lse - (l == 0 ? l0 : l1);
            lcnt++;
        }
    }
    #pragma unroll
    for (int off = 32; off; off >>= 1) {
        lsum += __shfl_down(lsum, off);
        lcnt += __shfl_down(lcnt, off);
    }
    __shared__ float wsum[4];
    __shared__ int wcnt[4];
    int wid = tid >> 6, lane = tid & 63;
    if (lane == 0) { wsum[wid] = lsum; wcnt[wid] = lcnt; }
    __syncthreads();
    if (tid == 0) {
        float S = wsum[0] + wsum[1] + wsum[2] + wsum[3];
        int C = wcnt[0] + wcnt[1] + wcnt[2] + wcnt[3];
        sl[b] = (C > 0) ? S / (float)C : 0.0f;
        validv[b] = (C > 0) ? 1.0f : 0.0f;
    }
}

// ---------------- loss reading logits directly (FALLBACK path) ------------------
__global__ void sr_loss(const int* __restrict__ lab, const float* __restrict__ logits,
                        float* __restrict__ mask_out, float* __restrict__ sl,
                        float* __restrict__ validv) {
    int b = blockIdx.x;
    int tid = threadIdx.x;
    float lsum = 0.f; int lcnt = 0;
    for (int s = tid; s < SEQ; s += 256) {
        int l = lab[b * SEQ + s];
        bool hdr = (l == 0) || (l == 1);
        mask_out[b * SEQ + s] = hdr ? 1.0f : 0.0f;
        if (hdr) {
            float l0 = logits[(b * SEQ + s) * 2];
            float l1 = logits[(b * SEQ + s) * 2 + 1];
            float mx = fmaxf(l0, l1);
            float lse = mx + logf(expf(l0 - mx) + expf(l1 - mx));
            lsum += lse - (l == 0 ? l0 : l1);
            lcnt++;
        }
    }
    #pragma unroll
    for (int off = 32; off; off >>= 1) {
        lsum += __shfl_down(lsum, off);
        lcnt += __shfl_down(lcnt, off);
    }
    __shared__ float wsum[4];
    __shared__ int wcnt[4];
    int wid = tid >> 6, lane = tid & 63;
    if (lane == 0) { wsum[wid] = lsum; wcnt[wid] = lcnt; }
    __syncthreads();
    if (tid == 0) {
        float S = wsum[0] + wsum[1] + wsum[2] + wsum[3];
        int C = wcnt[0] + wcnt[1] + wcnt[2] + wcnt[3];
        sl[b] = (C > 0) ? S / (float)C : 0.0f;
        validv[b] = (C > 0) ? 1.0f : 0.0f;
    }
}

__global__ void sr_final(const float* __restrict__ sl, const float* __restrict__ validv,
                         float* __restrict__ out) {
    if (threadIdx.x == 0) {
        float s = 0.f, v = 0.f;
        for (int b = 0; b < NB; ++b) { s += sl[b]; v += validv[b]; }
        out[0] = s / (v + 1e-6f);
    }
}

extern "C" void kernel_launch(void* const* d_in, const int* in_sizes, int n_in,
                              void* d_out, int out_size, void* d_ws, size_t ws_size,
                              hipStream_t stream) {
    const float* enc = (const float*)d_in[0];
    const int*   lab = (const int*)d_in[1];
    const float* W1  = (const float*)d_in[2];
    const float* b1  = (const float*)d_in[3];
    const float* W2  = (const float*)d_in[4];
    const float* b2  = (const float*)d_in[5];

    float* out     = (float*)d_out;
    float* loss    = out;
    float* logits  = out + 1;
    float* maskout = out + 1 + MROWS * 2;

    float* ws     = (float*)d_ws;
    float* femb   = ws;                            // 32768 f32
    float* fc     = ws + 32768;                    // 32768 f32
    float* sl     = ws + 65536;                    // 32
    float* validv = ws + 65568;                    // 32
    float* partg  = ws + 65600;                    // 524288 f32 (2 MB)
    __bf16* Bt    = (__bf16*)(ws + 65600 + 2 * 524288);  // 2 MB
    __bf16* Ab    = Bt + (size_t)HID * HID;              // 134.2 MB

    const size_t need = (65600u + 2u * 524288u) * 4u + (size_t)HID * HID * 2u
                      + (size_t)MROWS * HID * 2u;

    sr_conv_w1<<<1024, 256, 0, stream>>>(W1, Bt);
    sr_femb<<<32, 256, 0, stream>>>(enc, lab, femb);
    sr_fc<<<512, 256, 0, stream>>>(femb, W1, b1, fc);

    if (ws_size >= need) {
        sr_conv_enc<<<32768, 256, 0, stream>>>(enc, Ab);
        sr_gemm16<<<1024, 512, 0, stream>>>(Ab, Bt, fc, W2, partg);
        sr_loss_pg<<<32, 256, 0, stream>>>(lab, partg, b2, logits, maskout, sl, validv);
    } else {
        sr_init_logits<<<512, 256, 0, stream>>>(logits, b2);
        sr_gemm_fused<<<4096, 256, 0, stream>>>(enc, Bt, fc, W2, logits);
        sr_loss<<<32, 256, 0, stream>>>(lab, logits, maskout, sl, validv);
    }

    sr_final<<<1, 64, 0, stream>>>(sl, validv, loss);
}